// Round 7
// baseline (15.502 us; speedup 1.0000x reference)
//
#include <hip/hip_runtime.h>

#define NN   50000
#define NE   800000
#define CH   64
#define NREL 8
#define NWRD ((NN + 63) / 64)   // 782 bitmap words

typedef float f32x4 __attribute__((ext_vector_type(4)));
typedef int   i32x4 __attribute__((ext_vector_type(4)));

// Dispatch 1: 3125 blocks x 256.
//  Phase a (16 threads/node, float4): splice history row (~99.995% of nodes)
//  or out = x @ loop_w + bias for the ~2.5 uncached nodes. Splice writes are
//  nontemporal (streaming, no reuse) to keep L2 for the history gather.
//  Phase b (first 782 waves): ballot "hmap[node] < 0" -> 6.25 KB rare-node
//  bitmap in d_ws. Every word written every call -> deterministic.
__global__ __launch_bounds__(256)
void splice_and_flag(const float* __restrict__ x,
                     const float* __restrict__ loop_w,
                     const float* __restrict__ bias,
                     const float* __restrict__ hist,
                     const int* __restrict__ hmap,
                     float* __restrict__ out,
                     unsigned long long* __restrict__ bitmap) {
    int gtid = blockIdx.x * blockDim.x + threadIdx.x;   // [0, 800000)

    // ---- phase a: node splice / self-loop ----
    int n = gtid >> 4;
    int q = gtid & 15;
    int hm = hmap[n];
    f32x4* out4 = (f32x4*)out;
    if (hm >= 0) {
        f32x4 v = ((const f32x4*)hist)[hm * 16 + q];
        __builtin_nontemporal_store(v, &out4[n * 16 + q]);
    } else {
        int c0 = q * 4;
        f32x4 acc = ((const f32x4*)bias)[q];
        const float* xr = x + n * CH;
#pragma unroll 8
        for (int i = 0; i < CH; ++i) {
            float xv = xr[i];
            f32x4 w = *(const f32x4*)(loop_w + i * CH + c0);
            acc += xv * w;
        }
        out4[n * 16 + q] = acc;   // rare row: normal store (D2 atomics follow)
    }

    // ---- phase b: rare-node bitmap ----
    int wid = gtid >> 6;
    if (wid < NWRD) {
        int lane = threadIdx.x & 63;
        int node = (wid << 6) + lane;
        int h = (node < NN) ? hmap[node] : 0;
        unsigned long long m = __ballot(h < 0);
        if (lane == 0) bitmap[wid] = m;
    }
}

// Dispatch 2: 782 blocks x 256. Each thread: one int4 of dst (4 edges),
// nontemporal (pure stream), 4 probes of the L1-resident 6.25 KB bitmap.
// Qualifying edges (~40 grid-wide): whole wave computes the 64-channel
// message (lane = channel), atomicAdd into out[dst].
__global__ __launch_bounds__(256)
void scan_apply(const float* __restrict__ x,
                const float* __restrict__ W,
                const int* __restrict__ src,
                const int* __restrict__ dst,
                const int* __restrict__ et,
                const unsigned long long* __restrict__ bitmap,
                float* __restrict__ out) {
    int gtid = blockIdx.x * blockDim.x + threadIdx.x;   // int4 index
    if (gtid >= NE / 4) return;
    int lane = threadIdx.x & 63;
    int wbase = gtid - lane;                 // wave's first int4 index

    i32x4 d4 = __builtin_nontemporal_load(&((const i32x4*)dst)[gtid]);

#pragma unroll 4
    for (int k = 0; k < 4; ++k) {
        int d = d4[k];
        unsigned long long w = bitmap[d >> 6];
        bool need = (w >> (d & 63)) & 1ULL;
        unsigned long long mask = __ballot(need);
        while (mask) {
            int l = __ffsll((long long)mask) - 1;
            mask &= mask - 1;
            int e = ((wbase + l) << 2) + k;
            int dd = __shfl(d, l);
            int s  = src[e];
            int r  = et[e];
            const float* xr = x + s * CH;
            const float* wr = W + r * CH * CH + lane;
            float acc = 0.0f;
#pragma unroll 8
            for (int i = 0; i < CH; ++i)
                acc += xr[i] * wr[i * CH];
            atomicAdd(out + dd * CH + lane, acc);
        }
    }
}

// Fallback if ws is too small (won't trigger): R2 scheme.
__global__ void edge_fused_fb(const float* __restrict__ x,
                              const float* __restrict__ W,
                              const int* __restrict__ src,
                              const int* __restrict__ dst,
                              const int* __restrict__ et,
                              const int* __restrict__ hmap,
                              float* __restrict__ out) {
    int gtid = blockIdx.x * blockDim.x + threadIdx.x;
    int lane = threadIdx.x & 63;
    int e0 = gtid - lane;
    if (e0 >= NE) return;
    int d = dst[e0 + lane];
    unsigned long long mask = __ballot(hmap[d] < 0);
    while (mask) {
        int l = __ffsll((long long)mask) - 1;
        mask &= mask - 1;
        int e = e0 + l;
        int dd = __shfl(d, l);
        int s  = src[e];
        int r  = et[e];
        const float* xr = x + s * CH;
        const float* wr = W + r * CH * CH + lane;
        float acc = 0.0f;
#pragma unroll 8
        for (int i = 0; i < CH; ++i)
            acc += xr[i] * wr[i * CH];
        atomicAdd(out + dd * CH + lane, acc);
    }
}

extern "C" void kernel_launch(void* const* d_in, const int* in_sizes, int n_in,
                              void* d_out, int out_size, void* d_ws, size_t ws_size,
                              hipStream_t stream) {
    const float* x      = (const float*)d_in[0];
    const float* W      = (const float*)d_in[1];
    const float* loop_w = (const float*)d_in[2];
    const float* bias   = (const float*)d_in[3];
    const float* hist   = (const float*)d_in[4];
    const int*   src    = (const int*)d_in[5];
    const int*   dst    = (const int*)d_in[6];
    const int*   et     = (const int*)d_in[7];
    const int*   hmap   = (const int*)d_in[8];
    float* out = (float*)d_out;

    if (ws_size >= (size_t)NWRD * 8) {
        unsigned long long* bitmap = (unsigned long long*)d_ws;
        splice_and_flag<<<NN * 16 / 256, 256, 0, stream>>>(
            x, loop_w, bias, hist, hmap, out, bitmap);
        scan_apply<<<(NE / 4 + 255) / 256, 256, 0, stream>>>(
            x, W, src, dst, et, bitmap, out);
    } else {
        splice_and_flag<<<NN * 16 / 256, 256, 0, stream>>>(
            x, loop_w, bias, hist, hmap, out, (unsigned long long*)d_out);
        edge_fused_fb<<<(NE + 255) / 256, 256, 0, stream>>>(
            x, W, src, dst, et, hmap, out);
    }
}